// Round 12
// baseline (142.177 us; speedup 1.0000x reference)
//
#include <hip/hip_runtime.h>
#include <hip/hip_bf16.h>

typedef float f32x4 __attribute__((ext_vector_type(4)));
typedef short s16x8 __attribute__((ext_vector_type(8)));

#define SIGC 2379
#define KPAD 2432
#define NKT  76          // KPAD/32 k-tiles
#define SROW 2440        // padded LDS row
#define NPATH 12800

// Tiled layout for A and W (bf16): element (row r, k) lives at
//   ((r>>4)*NKT + (k>>5))*512 + ((k>>3)&3)*128 + (r&15)*8 + (k&7)
// 1KB tiles of [ks(4)][R(16)][kw(8)] — fragment-ready for 16x16x32 MFMA
// (per-lane frag offset = lane*16B, lane-linear), one lane-linear
// global_load_lds per tile.

__device__ inline void split2(float v, __hip_bfloat16* h, __hip_bfloat16* l) {
    __hip_bfloat16 hh = __float2bfloat16(v);
    *h = hh;
    *l = __float2bfloat16(v - __bfloat162float(hh));
}

__device__ inline void gload_lds16(const __hip_bfloat16* g, __hip_bfloat16* l) {
    __builtin_amdgcn_global_load_lds(
        (const __attribute__((address_space(1))) void*)g,
        (__attribute__((address_space(3))) void*)l,
        16, 0, 0);
}

// ---------------------------------------------------------------------------
// W convert: W[256][2379] fp32 -> tiled Wh/Wl bf16 hi+lo (pad zeroed)
// ---------------------------------------------------------------------------
__global__ __launch_bounds__(256) void wconv_kernel(const float* __restrict__ W,
                                                    __hip_bfloat16* __restrict__ Wh,
                                                    __hip_bfloat16* __restrict__ Wl)
{
    int k = blockIdx.x * 256 + threadIdx.x;
    int n = blockIdx.y;
    if (k >= KPAD) return;
    float v = (k < SIGC) ? W[(size_t)n * SIGC + k] : 0.0f;
    size_t off = ((size_t)(n >> 4) * NKT + (k >> 5)) * 512 + ((k >> 3) & 3) * 128 + (n & 15) * 8 + (k & 7);
    split2(v, &Wh[off], &Wl[off]);
}

// ---------------------------------------------------------------------------
// Signature kernel (proven): 4 waves/block, 4 pp-phases; at phase pp wave w
// computes path row = pp*4 + w -> 4 consecutive live rows -> cooperative
// 64B-contiguous copy-out. Register-only Chen scan; lane owns pairs
// p in {lane, lane+64, lane+128(<169)}.
// s3[ijk] += dx[k] * (s2[ij] + 0.5*dx[j]*(s1[i] + dx[i]/3))
// ---------------------------------------------------------------------------
__global__ __launch_bounds__(256) void sig_kernel(const float* __restrict__ x,
                                                  __hip_bfloat16* __restrict__ Ah,
                                                  __hip_bfloat16* __restrict__ Al_,
                                                  int r_start)
{
    __shared__ float inc_s[4][5][16];                        // [wave][step][channel]
    __shared__ __align__(16) __hip_bfloat16 hi_s[4][SROW];   // [wave] = row 4*pp+w
    __shared__ __align__(16) __hip_bfloat16 lo_s[4][SROW];

    const int t = threadIdx.x;
    const int w = t >> 6;
    const int lane = t & 63;

    const int p0 = lane;
    const int p1 = lane + 64;
    const int p2 = lane + 128;
    const bool has2 = (p2 < 169);
    const int i0 = p0 / 13, j0 = p0 - i0 * 13;
    const int i1 = p1 / 13, j1 = p1 - i1 * 13;
    const int i2 = p2 / 13, j2 = p2 - i2 * 13;   // used under has2

    for (int pp = 0; pp < 4; ++pp) {
        const int r = r_start + blockIdx.x * 16 + pp * 4 + w;
        const int nn = r & 7;
        const int jj = (r >> 3) & 63;
        const int ii = r >> 9;

        __syncthreads();   // guard inc_s / hi_s / lo_s reuse across pp
        if (lane < 13) {
            if (lane < 12) {
                const float* px = x + ((size_t)(nn * 12 + lane) * 1600 + ii * 64 + jj) * 5;
                float prev = 0.0f;
                #pragma unroll
                for (int l = 0; l < 5; ++l) {
                    float v = px[l];
                    inc_s[w][l][lane] = v - prev;
                    prev = v;
                }
            } else {
                inc_s[w][0][12] = 0.0f;
                #pragma unroll
                for (int l = 1; l < 5; ++l) inc_s[w][l][12] = 0.25f;
            }
        }
        __syncthreads();

        float s1i0 = 0.0f, s1i1 = 0.0f, s1i2 = 0.0f;
        float s2p0 = 0.0f, s2p1 = 0.0f, s2p2 = 0.0f;
        float s1own = 0.0f;
        float s3a[13], s3b[13], s3c[13];
        #pragma unroll
        for (int k = 0; k < 13; ++k) { s3a[k] = 0.0f; s3b[k] = 0.0f; s3c[k] = 0.0f; }

        for (int l = 0; l < 5; ++l) {
            float dxl[13];
            #pragma unroll
            for (int k = 0; k < 13; ++k) dxl[k] = inc_s[w][l][k];

            {   // pair 0
                float dxi = inc_s[w][l][i0];
                float dxj = inc_s[w][l][j0];
                float C   = s2p0 + 0.5f * dxj * (s1i0 + dxi * (1.0f / 3.0f));
                #pragma unroll
                for (int k = 0; k < 13; ++k) s3a[k] += dxl[k] * C;
                s2p0 += s1i0 * dxj + 0.5f * dxi * dxj;
                s1i0 += dxi;
            }
            {   // pair 1
                float dxi = inc_s[w][l][i1];
                float dxj = inc_s[w][l][j1];
                float C   = s2p1 + 0.5f * dxj * (s1i1 + dxi * (1.0f / 3.0f));
                #pragma unroll
                for (int k = 0; k < 13; ++k) s3b[k] += dxl[k] * C;
                s2p1 += s1i1 * dxj + 0.5f * dxi * dxj;
                s1i1 += dxi;
            }
            if (has2) {   // pair 2
                float dxi = inc_s[w][l][i2];
                float dxj = inc_s[w][l][j2];
                float C   = s2p2 + 0.5f * dxj * (s1i2 + dxi * (1.0f / 3.0f));
                #pragma unroll
                for (int k = 0; k < 13; ++k) s3c[k] += dxl[k] * C;
                s2p2 += s1i2 * dxj + 0.5f * dxi * dxj;
                s1i2 += dxi;
            }
            if (lane < 13) s1own += inc_s[w][l][lane];
        }

        // ---- write sig row into this wave's LDS row (hi/lo) ----
        if (lane < 13) split2(s1own, &hi_s[w][lane], &lo_s[w][lane]);
        split2(s2p0, &hi_s[w][13 + p0], &lo_s[w][13 + p0]);
        split2(s2p1, &hi_s[w][13 + p1], &lo_s[w][13 + p1]);
        if (has2) split2(s2p2, &hi_s[w][13 + p2], &lo_s[w][13 + p2]);
        #pragma unroll
        for (int k = 0; k < 13; ++k) split2(s3a[k], &hi_s[w][182 + p0 * 13 + k], &lo_s[w][182 + p0 * 13 + k]);
        #pragma unroll
        for (int k = 0; k < 13; ++k) split2(s3b[k], &hi_s[w][182 + p1 * 13 + k], &lo_s[w][182 + p1 * 13 + k]);
        if (has2) {
            #pragma unroll
            for (int k = 0; k < 13; ++k) split2(s3c[k], &hi_s[w][182 + p2 * 13 + k], &lo_s[w][182 + p2 * 13 + k]);
        }
        if (lane < KPAD - SIGC) {   // zero pad 2379..2431
            hi_s[w][SIGC + lane] = __float2bfloat16(0.0f);
            lo_s[w][SIGC + lane] = __float2bfloat16(0.0f);
        }

        __syncthreads();   // all 4 rows complete before cooperative copy-out

        // ---- block-cooperative coalesced copy-out (64B bursts) ----
        const int rtl = blockIdx.x;
        const int rr = t & 3, ks = (t >> 2) & 3, ts = t >> 4;
        #pragma unroll
        for (int it2 = 0; it2 < 5; ++it2) {
            int kt = it2 * 16 + ts;
            if (kt < NKT) {
                size_t off = ((size_t)rtl * NKT + kt) * 512 + ks * 128 + (pp * 4 + rr) * 8;
                int lidx = kt * 32 + ks * 8;
                *reinterpret_cast<int4*>(Ah + off)  = *reinterpret_cast<const int4*>(&hi_s[rr][lidx]);
                *reinterpret_cast<int4*>(Al_ + off) = *reinterpret_cast<const int4*>(&lo_s[rr][lidx]);
            }
        }
    }
}

// ---------------------------------------------------------------------------
// Split-bf16 GEMM, SINGLE-WAVE blocks (64 threads), wave tile 64x128:
// out[m][o] = bias[o] + sum_k (AhWh + AhWl + AlWh)
// No barriers at all: the wave owns its whole LDS — fully self-paced
// gload_lds pipeline, depth-2 counted s_waitcnt vmcnt(48). Per k-tile:
// 24 KB operands (A 8 tiles hi/lo + W 16 tiles hi/lo) feed 96 MFMAs
// (466 cy) — LDS traffic (~430 cy) finally under the MFMA pipe.
// Grid = nmblk x 2 n-halves (~200 blocks, one per CU); W (2.5 MB tiled)
// is L2-resident. bid = q*16 + h*8 + x8, mIdx = q*8+x8 pins both n-halves
// of an m-block to one XCD slot (A's 2nd read = L2 hit, proven r5/r11).
// Epilogue: fp32 transpose via LDS -> coalesced float4 stores with bias.
// ---------------------------------------------------------------------------
__global__ __launch_bounds__(64) void gemm_kernel(const __hip_bfloat16* __restrict__ Ah,
                                                  const __hip_bfloat16* __restrict__ Al_,
                                                  const __hip_bfloat16* __restrict__ Wh,
                                                  const __hip_bfloat16* __restrict__ Wl,
                                                  const float* __restrict__ b,
                                                  float* __restrict__ out,
                                                  int r_start, int nmblk)
{
    // 3 buffers x 24 tiles x 512 bf16 = 72 KB. Tiles: [0-3]=Ah, [4-7]=Al,
    // [8-15]=Wh(nh0,nh1), [16-23]=Wl.
    __shared__ __align__(16) __hip_bfloat16 L[3][24 * 512];

    const int bid = blockIdx.x;
    const int x8 = bid & 7;
    const int h = (bid >> 3) & 1;
    const int q = bid >> 4;
    const int mIdx = q * 8 + x8;
    if (mIdx >= nmblk) return;

    const int lane = threadIdx.x;
    const int rt0 = mIdx * 4;      // 4 m-row-tiles (64 paths)
    const int nt0 = h * 8;         // 8 n-row-tiles (128 outputs)

    f32x4 acc[4][8] = {};

    auto stage = [&](int buf, int kt) {
        __hip_bfloat16* Lb = &L[buf][0];
        #pragma unroll
        for (int s = 0; s < 4; ++s)
            gload_lds16(Ah  + ((size_t)(rt0 + s) * NKT + kt) * 512 + lane * 8, Lb + s * 512);
        #pragma unroll
        for (int s = 0; s < 4; ++s)
            gload_lds16(Al_ + ((size_t)(rt0 + s) * NKT + kt) * 512 + lane * 8, Lb + (4 + s) * 512);
        #pragma unroll
        for (int s = 0; s < 8; ++s)
            gload_lds16(Wh  + ((size_t)(nt0 + s) * NKT + kt) * 512 + lane * 8, Lb + (8 + s) * 512);
        #pragma unroll
        for (int s = 0; s < 8; ++s)
            gload_lds16(Wl  + ((size_t)(nt0 + s) * NKT + kt) * 512 + lane * 8, Lb + (16 + s) * 512);
    };

    auto compute = [&](int buf) {
        const __hip_bfloat16* Lb = &L[buf][0];
        s16x8 ah[4], al4[4];
        #pragma unroll
        for (int mm = 0; mm < 4; ++mm) {
            ah[mm]  = *reinterpret_cast<const s16x8*>(&Lb[mm * 512 + lane * 8]);
            al4[mm] = *reinterpret_cast<const s16x8*>(&Lb[(4 + mm) * 512 + lane * 8]);
        }
        #pragma unroll
        for (int nh = 0; nh < 2; ++nh) {
            s16x8 bh[4], bl4[4];
            #pragma unroll
            for (int nn = 0; nn < 4; ++nn) {
                bh[nn]  = *reinterpret_cast<const s16x8*>(&Lb[(8 + nh * 4 + nn) * 512 + lane * 8]);
                bl4[nn] = *reinterpret_cast<const s16x8*>(&Lb[(16 + nh * 4 + nn) * 512 + lane * 8]);
            }
            #pragma unroll
            for (int nn = 0; nn < 4; ++nn)
                #pragma unroll
                for (int mm = 0; mm < 4; ++mm) {
                    acc[mm][nh * 4 + nn] = __builtin_amdgcn_mfma_f32_16x16x32_bf16(ah[mm],  bh[nn],  acc[mm][nh * 4 + nn], 0, 0, 0);
                    acc[mm][nh * 4 + nn] = __builtin_amdgcn_mfma_f32_16x16x32_bf16(ah[mm],  bl4[nn], acc[mm][nh * 4 + nn], 0, 0, 0);
                    acc[mm][nh * 4 + nn] = __builtin_amdgcn_mfma_f32_16x16x32_bf16(al4[mm], bh[nn],  acc[mm][nh * 4 + nn], 0, 0, 0);
                }
        }
    };

    stage(0, 0);
    stage(1, 1);
    int b0 = 0, b1 = 1, b2 = 2;

    #pragma unroll 1
    for (int kt = 0; kt < NKT; ++kt) {
        if (kt + 2 < NKT) {
            stage(b2, kt + 2);
            asm volatile("s_waitcnt vmcnt(48)" ::: "memory");   // drain stage kt; 2 stages in flight
        } else if (kt + 1 < NKT) {
            asm volatile("s_waitcnt vmcnt(24)" ::: "memory");
        } else {
            asm volatile("s_waitcnt vmcnt(0)" ::: "memory");
        }
        compute(b0);
        int tmp = b0; b0 = b1; b1 = b2; b2 = tmp;
    }

    // ---- epilogue (single wave, no barriers): transpose via LDS ----
    float* T = (float*)&L[0][0];   // 64 x 132 fp32 = 33.8 KB
    #pragma unroll
    for (int mm = 0; mm < 4; ++mm)
        #pragma unroll
        for (int nn = 0; nn < 8; ++nn)
            #pragma unroll
            for (int rr = 0; rr < 4; ++rr) {
                int p = mm * 16 + (lane >> 4) * 4 + rr;   // row in 0..63
                int o = nn * 16 + (lane & 15);            // col in 0..127
                T[p * 132 + o] = acc[mm][nn][rr];
            }

    const int pbase = r_start + mIdx * 64;
    const int ii = pbase >> 9;
    const int jj0 = (pbase >> 3) & 63;   // multiple of 8
    #pragma unroll
    for (int o2 = 0; o2 < 2; ++o2) {
        int col = o2 * 64 + lane;
        int o = h * 128 + col;
        float bo = b[o];
        #pragma unroll
        for (int ni = 0; ni < 8; ++ni) {
            float v[8];
            #pragma unroll
            for (int qq = 0; qq < 8; ++qq) v[qq] = T[(qq * 8 + ni) * 132 + col] + bo;
            float* dst = out + (size_t)(ni * 256 + o) * 1600 + ii * 64 + jj0;
            *reinterpret_cast<float4*>(dst)     = make_float4(v[0], v[1], v[2], v[3]);
            *reinterpret_cast<float4*>(dst + 4) = make_float4(v[4], v[5], v[6], v[7]);
        }
    }
}

// ---------------------------------------------------------------------------
extern "C" void kernel_launch(void* const* d_in, const int* in_sizes, int n_in,
                              void* d_out, int out_size, void* d_ws, size_t ws_size,
                              hipStream_t stream)
{
    const float* x = (const float*)d_in[0];
    const float* W = (const float*)d_in[1];
    const float* b = (const float*)d_in[2];
    float* out = (float*)d_out;

    char* ws = (char*)d_ws;
    __hip_bfloat16* Wh = (__hip_bfloat16*)ws;
    __hip_bfloat16* Wl = Wh + (size_t)16 * NKT * 512;
    size_t a_off = (((size_t)16 * NKT * 512 * 2 * 2) + 255) & ~(size_t)255;

    // per-path bytes: A hi/lo = KPAD*2*2 = 9728
    size_t avail = (ws_size > a_off) ? ws_size - a_off : 0;
    long long maxp = (long long)(avail / ((size_t)KPAD * 4));
    int chunk = (int)((maxp / 128) * 128);
    if (chunk > NPATH) chunk = NPATH;
    if (chunk < 128) chunk = 128;

    __hip_bfloat16* Ah = (__hip_bfloat16*)(ws + a_off);
    __hip_bfloat16* Al_ = Ah + (size_t)chunk * KPAD;

    wconv_kernel<<<dim3(10, 256), 256, 0, stream>>>(W, Wh, Wl);

    for (int r0 = 0; r0 < NPATH; r0 += chunk) {
        int cnt = NPATH - r0;
        if (cnt > chunk) cnt = chunk;
        int nmblk = cnt / 64;                      // 64-path m-blocks
        int nblk = ((nmblk + 7) / 8) * 16;         // q*16 + h*8 + x8 swizzle
        sig_kernel<<<dim3(cnt / 16), 256, 0, stream>>>(x, Ah, Al_, r0);
        gemm_kernel<<<dim3(nblk), 64, 0, stream>>>(Ah, Al_, Wh, Wl, b, out, r0, nmblk);
    }
}

// Round 13
// 138.833 us; speedup vs baseline: 1.0241x; 1.0241x over previous
//
#include <hip/hip_runtime.h>
#include <hip/hip_bf16.h>

typedef float f32x4 __attribute__((ext_vector_type(4)));
typedef short s16x8 __attribute__((ext_vector_type(8)));

#define SIGC 2379
#define KPAD 2432
#define NKT  76          // KPAD/32 k-tiles
#define SROW 2440        // padded LDS row
#define NPATH 12800

// Tiled layout for A and W (bf16): element (row r, k) lives at
//   ((r>>4)*NKT + (k>>5))*512 + ((k>>3)&3)*128 + (r&15)*8 + (k&7)
// 1KB tiles of [ks(4)][R(16)][kw(8)] — fragment-ready for 16x16x32 MFMA
// (per-lane frag offset = lane*16B, lane-linear), one lane-linear
// global_load_lds per tile.

__device__ inline void split2(float v, __hip_bfloat16* h, __hip_bfloat16* l) {
    __hip_bfloat16 hh = __float2bfloat16(v);
    *h = hh;
    *l = __float2bfloat16(v - __bfloat162float(hh));
}

__device__ inline void gload_lds16(const __hip_bfloat16* g, __hip_bfloat16* l) {
    __builtin_amdgcn_global_load_lds(
        (const __attribute__((address_space(1))) void*)g,
        (__attribute__((address_space(3))) void*)l,
        16, 0, 0);
}

// ---------------------------------------------------------------------------
// W convert: W[256][2379] fp32 -> tiled Wh/Wl bf16 hi+lo (pad zeroed)
// ---------------------------------------------------------------------------
__global__ __launch_bounds__(256) void wconv_kernel(const float* __restrict__ W,
                                                    __hip_bfloat16* __restrict__ Wh,
                                                    __hip_bfloat16* __restrict__ Wl)
{
    int k = blockIdx.x * 256 + threadIdx.x;
    int n = blockIdx.y;
    if (k >= KPAD) return;
    float v = (k < SIGC) ? W[(size_t)n * SIGC + k] : 0.0f;
    size_t off = ((size_t)(n >> 4) * NKT + (k >> 5)) * 512 + ((k >> 3) & 3) * 128 + (n & 15) * 8 + (k & 7);
    split2(v, &Wh[off], &Wl[off]);
}

// ---------------------------------------------------------------------------
// Signature kernel (proven): 4 waves/block, 4 pp-phases; at phase pp wave w
// computes path row = pp*4 + w -> 4 consecutive live rows -> cooperative
// 64B-contiguous copy-out. Register-only Chen scan; lane owns pairs
// p in {lane, lane+64, lane+128(<169)}.
// s3[ijk] += dx[k] * (s2[ij] + 0.5*dx[j]*(s1[i] + dx[i]/3))
// ---------------------------------------------------------------------------
__global__ __launch_bounds__(256) void sig_kernel(const float* __restrict__ x,
                                                  __hip_bfloat16* __restrict__ Ah,
                                                  __hip_bfloat16* __restrict__ Al_,
                                                  int r_start)
{
    __shared__ float inc_s[4][5][16];                        // [wave][step][channel]
    __shared__ __align__(16) __hip_bfloat16 hi_s[4][SROW];   // [wave] = row 4*pp+w
    __shared__ __align__(16) __hip_bfloat16 lo_s[4][SROW];

    const int t = threadIdx.x;
    const int w = t >> 6;
    const int lane = t & 63;

    const int p0 = lane;
    const int p1 = lane + 64;
    const int p2 = lane + 128;
    const bool has2 = (p2 < 169);
    const int i0 = p0 / 13, j0 = p0 - i0 * 13;
    const int i1 = p1 / 13, j1 = p1 - i1 * 13;
    const int i2 = p2 / 13, j2 = p2 - i2 * 13;   // used under has2

    for (int pp = 0; pp < 4; ++pp) {
        const int r = r_start + blockIdx.x * 16 + pp * 4 + w;
        const int nn = r & 7;
        const int jj = (r >> 3) & 63;
        const int ii = r >> 9;

        __syncthreads();   // guard inc_s / hi_s / lo_s reuse across pp
        if (lane < 13) {
            if (lane < 12) {
                const float* px = x + ((size_t)(nn * 12 + lane) * 1600 + ii * 64 + jj) * 5;
                float prev = 0.0f;
                #pragma unroll
                for (int l = 0; l < 5; ++l) {
                    float v = px[l];
                    inc_s[w][l][lane] = v - prev;
                    prev = v;
                }
            } else {
                inc_s[w][0][12] = 0.0f;
                #pragma unroll
                for (int l = 1; l < 5; ++l) inc_s[w][l][12] = 0.25f;
            }
        }
        __syncthreads();

        float s1i0 = 0.0f, s1i1 = 0.0f, s1i2 = 0.0f;
        float s2p0 = 0.0f, s2p1 = 0.0f, s2p2 = 0.0f;
        float s1own = 0.0f;
        float s3a[13], s3b[13], s3c[13];
        #pragma unroll
        for (int k = 0; k < 13; ++k) { s3a[k] = 0.0f; s3b[k] = 0.0f; s3c[k] = 0.0f; }

        for (int l = 0; l < 5; ++l) {
            float dxl[13];
            #pragma unroll
            for (int k = 0; k < 13; ++k) dxl[k] = inc_s[w][l][k];

            {   // pair 0
                float dxi = inc_s[w][l][i0];
                float dxj = inc_s[w][l][j0];
                float C   = s2p0 + 0.5f * dxj * (s1i0 + dxi * (1.0f / 3.0f));
                #pragma unroll
                for (int k = 0; k < 13; ++k) s3a[k] += dxl[k] * C;
                s2p0 += s1i0 * dxj + 0.5f * dxi * dxj;
                s1i0 += dxi;
            }
            {   // pair 1
                float dxi = inc_s[w][l][i1];
                float dxj = inc_s[w][l][j1];
                float C   = s2p1 + 0.5f * dxj * (s1i1 + dxi * (1.0f / 3.0f));
                #pragma unroll
                for (int k = 0; k < 13; ++k) s3b[k] += dxl[k] * C;
                s2p1 += s1i1 * dxj + 0.5f * dxi * dxj;
                s1i1 += dxi;
            }
            if (has2) {   // pair 2
                float dxi = inc_s[w][l][i2];
                float dxj = inc_s[w][l][j2];
                float C   = s2p2 + 0.5f * dxj * (s1i2 + dxi * (1.0f / 3.0f));
                #pragma unroll
                for (int k = 0; k < 13; ++k) s3c[k] += dxl[k] * C;
                s2p2 += s1i2 * dxj + 0.5f * dxi * dxj;
                s1i2 += dxi;
            }
            if (lane < 13) s1own += inc_s[w][l][lane];
        }

        // ---- write sig row into this wave's LDS row (hi/lo) ----
        if (lane < 13) split2(s1own, &hi_s[w][lane], &lo_s[w][lane]);
        split2(s2p0, &hi_s[w][13 + p0], &lo_s[w][13 + p0]);
        split2(s2p1, &hi_s[w][13 + p1], &lo_s[w][13 + p1]);
        if (has2) split2(s2p2, &hi_s[w][13 + p2], &lo_s[w][13 + p2]);
        #pragma unroll
        for (int k = 0; k < 13; ++k) split2(s3a[k], &hi_s[w][182 + p0 * 13 + k], &lo_s[w][182 + p0 * 13 + k]);
        #pragma unroll
        for (int k = 0; k < 13; ++k) split2(s3b[k], &hi_s[w][182 + p1 * 13 + k], &lo_s[w][182 + p1 * 13 + k]);
        if (has2) {
            #pragma unroll
            for (int k = 0; k < 13; ++k) split2(s3c[k], &hi_s[w][182 + p2 * 13 + k], &lo_s[w][182 + p2 * 13 + k]);
        }
        if (lane < KPAD - SIGC) {   // zero pad 2379..2431
            hi_s[w][SIGC + lane] = __float2bfloat16(0.0f);
            lo_s[w][SIGC + lane] = __float2bfloat16(0.0f);
        }

        __syncthreads();   // all 4 rows complete before cooperative copy-out

        // ---- block-cooperative coalesced copy-out (64B bursts) ----
        const int rtl = blockIdx.x;
        const int rr = t & 3, ks = (t >> 2) & 3, ts = t >> 4;
        #pragma unroll
        for (int it2 = 0; it2 < 5; ++it2) {
            int kt = it2 * 16 + ts;
            if (kt < NKT) {
                size_t off = ((size_t)rtl * NKT + kt) * 512 + ks * 128 + (pp * 4 + rr) * 8;
                int lidx = kt * 32 + ks * 8;
                *reinterpret_cast<int4*>(Ah + off)  = *reinterpret_cast<const int4*>(&hi_s[rr][lidx]);
                *reinterpret_cast<int4*>(Al_ + off) = *reinterpret_cast<const int4*>(&lo_s[rr][lidx]);
            }
        }
    }
}

// ---------------------------------------------------------------------------
// Split-bf16 GEMM, SINGLE-WAVE blocks (64 threads), wave tile 64x128:
// out[m][o] = bias[o] + sum_k (AhWh + AhWl + AlWh)
// Self-paced (no barriers), 3-buffer depth-2 gload_lds pipeline with the
// counted wait ISSUED BEFORE the next stage (peak outstanding 48 <= 63 —
// r12 peaked at 72 and stalled on the hardware vmcnt cap).
// THREE-PASS MFMA: pass1 all 32 cells ah*bh, pass2 ah*bl, pass3 al*bh —
// dependent reuse of an acc is 32 MFMAs apart (~155cy > accumulate latency),
// vs r12's 3 chained MFMAs per cell (naked latency at 1 wave/SIMD).
// Grid = nmblk x 2 n-halves (~200 blocks, 1/CU); W tiled 5 MB L2-resident;
// bid = q*16 + h*8 + x8 pins both n-halves of an m-block to one XCD slot.
// ---------------------------------------------------------------------------
__global__ __launch_bounds__(64) void gemm_kernel(const __hip_bfloat16* __restrict__ Ah,
                                                  const __hip_bfloat16* __restrict__ Al_,
                                                  const __hip_bfloat16* __restrict__ Wh,
                                                  const __hip_bfloat16* __restrict__ Wl,
                                                  const float* __restrict__ b,
                                                  float* __restrict__ out,
                                                  int r_start, int nmblk)
{
    // 3 buffers x 24 tiles x 512 bf16 = 72 KB. Tiles: [0-3]=Ah, [4-7]=Al,
    // [8-15]=Wh, [16-23]=Wl.
    __shared__ __align__(16) __hip_bfloat16 L[3][24 * 512];

    const int bid = blockIdx.x;
    const int x8 = bid & 7;
    const int h = (bid >> 3) & 1;
    const int q = bid >> 4;
    const int mIdx = q * 8 + x8;
    if (mIdx >= nmblk) return;

    const int lane = threadIdx.x;
    const int rt0 = mIdx * 4;      // 4 m-row-tiles (64 paths)
    const int nt0 = h * 8;         // 8 n-row-tiles (128 outputs)

    f32x4 acc[4][8] = {};

    auto stage = [&](int buf, int kt) {
        __hip_bfloat16* Lb = &L[buf][0];
        #pragma unroll
        for (int s = 0; s < 4; ++s)
            gload_lds16(Ah  + ((size_t)(rt0 + s) * NKT + kt) * 512 + lane * 8, Lb + s * 512);
        #pragma unroll
        for (int s = 0; s < 4; ++s)
            gload_lds16(Al_ + ((size_t)(rt0 + s) * NKT + kt) * 512 + lane * 8, Lb + (4 + s) * 512);
        #pragma unroll
        for (int s = 0; s < 8; ++s)
            gload_lds16(Wh  + ((size_t)(nt0 + s) * NKT + kt) * 512 + lane * 8, Lb + (8 + s) * 512);
        #pragma unroll
        for (int s = 0; s < 8; ++s)
            gload_lds16(Wl  + ((size_t)(nt0 + s) * NKT + kt) * 512 + lane * 8, Lb + (16 + s) * 512);
    };

    auto compute = [&](int buf) {
        const __hip_bfloat16* Lb = &L[buf][0];
        s16x8 ah[4], al4[4], bh[8], bl4[8];
        #pragma unroll
        for (int mm = 0; mm < 4; ++mm) {
            ah[mm]  = *reinterpret_cast<const s16x8*>(&Lb[mm * 512 + lane * 8]);
            al4[mm] = *reinterpret_cast<const s16x8*>(&Lb[(4 + mm) * 512 + lane * 8]);
        }
        #pragma unroll
        for (int nn = 0; nn < 8; ++nn) {
            bh[nn]  = *reinterpret_cast<const s16x8*>(&Lb[(8 + nn) * 512 + lane * 8]);
            bl4[nn] = *reinterpret_cast<const s16x8*>(&Lb[(16 + nn) * 512 + lane * 8]);
        }
        // pass 1: all cells ah*bh (32 independent MFMAs)
        #pragma unroll
        for (int nn = 0; nn < 8; ++nn)
            #pragma unroll
            for (int mm = 0; mm < 4; ++mm)
                acc[mm][nn] = __builtin_amdgcn_mfma_f32_16x16x32_bf16(ah[mm], bh[nn], acc[mm][nn], 0, 0, 0);
        // pass 2: all cells ah*bl
        #pragma unroll
        for (int nn = 0; nn < 8; ++nn)
            #pragma unroll
            for (int mm = 0; mm < 4; ++mm)
                acc[mm][nn] = __builtin_amdgcn_mfma_f32_16x16x32_bf16(ah[mm], bl4[nn], acc[mm][nn], 0, 0, 0);
        // pass 3: all cells al*bh
        #pragma unroll
        for (int nn = 0; nn < 8; ++nn)
            #pragma unroll
            for (int mm = 0; mm < 4; ++mm)
                acc[mm][nn] = __builtin_amdgcn_mfma_f32_16x16x32_bf16(al4[mm], bh[nn], acc[mm][nn], 0, 0, 0);
    };

    stage(0, 0);
    stage(1, 1);
    int b0 = 0, b1 = 1, b2 = 2;

    #pragma unroll 1
    for (int kt = 0; kt < NKT; ++kt) {
        // counted wait FIRST (oldest stage drained; peak outstanding 48 <= 63)
        if (kt + 1 < NKT) asm volatile("s_waitcnt vmcnt(24)" ::: "memory");
        else              asm volatile("s_waitcnt vmcnt(0)"  ::: "memory");
        if (kt + 2 < NKT) stage(b2, kt + 2);
        compute(b0);
        int tmp = b0; b0 = b1; b1 = b2; b2 = tmp;
    }

    // ---- epilogue (single wave, no barriers): transpose via LDS ----
    float* T = (float*)&L[0][0];   // 64 x 132 fp32 = 33.8 KB
    #pragma unroll
    for (int mm = 0; mm < 4; ++mm)
        #pragma unroll
        for (int nn = 0; nn < 8; ++nn)
            #pragma unroll
            for (int rr = 0; rr < 4; ++rr) {
                int p = mm * 16 + (lane >> 4) * 4 + rr;   // row in 0..63
                int o = nn * 16 + (lane & 15);            // col in 0..127
                T[p * 132 + o] = acc[mm][nn][rr];
            }

    const int pbase = r_start + mIdx * 64;
    const int ii = pbase >> 9;
    const int jj0 = (pbase >> 3) & 63;   // multiple of 8
    #pragma unroll
    for (int o2 = 0; o2 < 2; ++o2) {
        int col = o2 * 64 + lane;
        int o = h * 128 + col;
        float bo = b[o];
        #pragma unroll
        for (int ni = 0; ni < 8; ++ni) {
            float v[8];
            #pragma unroll
            for (int qq = 0; qq < 8; ++qq) v[qq] = T[(qq * 8 + ni) * 132 + col] + bo;
            float* dst = out + (size_t)(ni * 256 + o) * 1600 + ii * 64 + jj0;
            *reinterpret_cast<float4*>(dst)     = make_float4(v[0], v[1], v[2], v[3]);
            *reinterpret_cast<float4*>(dst + 4) = make_float4(v[4], v[5], v[6], v[7]);
        }
    }
}

// ---------------------------------------------------------------------------
extern "C" void kernel_launch(void* const* d_in, const int* in_sizes, int n_in,
                              void* d_out, int out_size, void* d_ws, size_t ws_size,
                              hipStream_t stream)
{
    const float* x = (const float*)d_in[0];
    const float* W = (const float*)d_in[1];
    const float* b = (const float*)d_in[2];
    float* out = (float*)d_out;

    char* ws = (char*)d_ws;
    __hip_bfloat16* Wh = (__hip_bfloat16*)ws;
    __hip_bfloat16* Wl = Wh + (size_t)16 * NKT * 512;
    size_t a_off = (((size_t)16 * NKT * 512 * 2 * 2) + 255) & ~(size_t)255;

    // per-path bytes: A hi/lo = KPAD*2*2 = 9728
    size_t avail = (ws_size > a_off) ? ws_size - a_off : 0;
    long long maxp = (long long)(avail / ((size_t)KPAD * 4));
    int chunk = (int)((maxp / 128) * 128);
    if (chunk > NPATH) chunk = NPATH;
    if (chunk < 128) chunk = 128;

    __hip_bfloat16* Ah = (__hip_bfloat16*)(ws + a_off);
    __hip_bfloat16* Al_ = Ah + (size_t)chunk * KPAD;

    wconv_kernel<<<dim3(10, 256), 256, 0, stream>>>(W, Wh, Wl);

    for (int r0 = 0; r0 < NPATH; r0 += chunk) {
        int cnt = NPATH - r0;
        if (cnt > chunk) cnt = chunk;
        int nmblk = cnt / 64;                      // 64-path m-blocks
        int nblk = ((nmblk + 7) / 8) * 16;         // q*16 + h*8 + x8 swizzle
        sig_kernel<<<dim3(cnt / 16), 256, 0, stream>>>(x, Ah, Al_, r0);
        gemm_kernel<<<dim3(nblk), 64, 0, stream>>>(Ah, Al_, Wh, Wl, b, out, r0, nmblk);
    }
}